// Round 7
// baseline (113.285 us; speedup 1.0000x reference)
//
#include <hip/hip_runtime.h>

// Problem constants (fixed by reference)
#define GS    256
#define PARAM 128
#define KC    32
#define I1    64
#define I2    32
#define PK    96        // PARAM - KC
#define B_    4
#define NROWS (B_ * GS) // 1024
#define EPS   1e-3f
#define KDIV_INV (1.0f / 16.0f)
#define RPB   4         // rows per block in kernel B (256 blocks = 1/CU)

// Workspace layout (float offsets)
constexpr int U_OFF   = 0;                   // NROWS*I1
constexpr int W_OFF   = NROWS * I1;
constexpr int M2F_OFF = 2 * NROWS * I1;      // I1*I2
constexpr int C2_OFF  = M2F_OFF + I1 * I2;   // I2
constexpr int M3F_OFF = C2_OFF + I2;         // I2*PK
constexpr int C3_OFF  = M3F_OFF + I2 * PK;   // PK
constexpr int C1_OFF  = C3_OFF + PK;         // I1

__device__ __forceinline__ float rdlane(float v, int l) {
    return __uint_as_float(__builtin_amdgcn_readlane(__float_as_uint(v), l));
}

// Kernel A: one block per row. 256 thr = 64 i-lanes x 4 quarter-dots.
// u = val.(M1top - M1bot) = T - W; compute T and W (1 load per MAC each).
__global__ __launch_bounds__(256) void glmlp_precompute(
    const float* __restrict__ val, const float* __restrict__ M1,
    const float* __restrict__ B1,
    const float* __restrict__ M2, const float* __restrict__ B2,
    const float* __restrict__ M3, const float* __restrict__ B3,
    const float* __restrict__ g1, const float* __restrict__ b1,
    const float* __restrict__ m1, const float* __restrict__ v1,
    const float* __restrict__ g2, const float* __restrict__ b2,
    const float* __restrict__ m2, const float* __restrict__ v2,
    const float* __restrict__ g3, const float* __restrict__ b3,
    const float* __restrict__ m3, const float* __restrict__ v3,
    float* __restrict__ ws, float* __restrict__ out)
{
    const int blk = blockIdx.x;
    const int t = threadIdx.x;

    if (blk < NROWS) {
        __shared__ float vrow[PARAM];
        __shared__ float red[4][I1];
        const int r = blk;
        if (t < PARAM) vrow[t] = val[r * PARAM + t];
        // exact copy: con = val[:, :, :KC] (direct from global; no barrier dep)
        if (t < KC) out[r * PARAM + t] = val[r * PARAM + t];
        __syncthreads();

        const int i = t & (I1 - 1);
        const int q = t >> 6;                         // 0..3
        // q=0,1 -> T (M1 top half); q=2,3 -> W (M1 bottom half)
        const float* __restrict__ Mb = M1 + ((q >> 1) ? (PARAM * I1) : 0);
        const int p0 = (q & 1) * 64;
        float aa = 0.f, bb = 0.f;                     // dual chains (dep 32)
        #pragma unroll 8
        for (int p = 0; p < 64; p += 2) {
            aa = fmaf(vrow[p0 + p],     Mb[(p0 + p) * I1 + i],     aa);
            bb = fmaf(vrow[p0 + p + 1], Mb[(p0 + p + 1) * I1 + i], bb);
        }
        red[q][i] = aa + bb;
        __syncthreads();

        if (q == 0) {
            const float T  = red[0][i] + red[1][i];
            const float Wv = red[2][i] + red[3][i];
            const float s1 = g1[i] * rsqrtf(v1[i] + EPS);
            ws[U_OFF + r * I1 + i] = (T - Wv) * s1;
            ws[W_OFF + r * I1 + i] = Wv * s1;
        }
    } else {
        // BN folding block
        if (t < I1) {
            const float s1 = g1[t] * rsqrtf(v1[t] + EPS);
            ws[C1_OFF + t] = B1[t] * s1 + b1[t] - m1[t] * s1;
        }
        if (t < I2) {
            const float s2 = g2[t] * rsqrtf(v2[t] + EPS);
            ws[C2_OFF + t] = B2[t] * s2 + b2[t] - m2[t] * s2;
        }
        if (t < PK) {
            const float s3 = g3[t] * rsqrtf(v3[t] + EPS);
            ws[C3_OFF + t] = B3[t] * s3 + b3[t] - m3[t] * s3;
        }
        for (int idx = t; idx < I1 * I2; idx += 256) {
            const int j = idx & (I2 - 1);
            const float s2 = g2[j] * rsqrtf(v2[j] + EPS);
            ws[M2F_OFF + idx] = M2[idx] * s2;
        }
        for (int idx = t; idx < I2 * PK; idx += 256) {
            const int k = idx % PK;
            const float s3 = g3[k] * rsqrtf(v3[k] + EPS);
            ws[M3F_OFF + idx] = M3[idx] * s3;
        }
    }
}

// Kernel B: PERSISTENT — 256 blocks (1 per CU), each owning RPB=4 consecutive
// rows (same batch: RPB divides GS). Weight preload (~130 L2-latency-bound
// loads into per-lane registers) is paid once per block instead of once per
// row (4x amortization vs r6), and the grid runs in a single scheduling
// round with no occupancy-dependent tail.
// Per row: compact mask, pair loop with 2-deep W prefetch, readlane-only MLP
// (math token-identical to r6). Weights stay in per-lane REGISTERS — proven
// to allocate in this standalone context (fused/cg variants spilled to 80
// VGPR three rounds running).
__global__ __launch_bounds__(256) void glmlp_pairs(
    const float* __restrict__ mat, const float* __restrict__ ws,
    float* __restrict__ out)
{
    __shared__ int   acty[GS];          // 1 KB
    __shared__ float partial[4][PK];    // 1.5 KB
    __shared__ int   cnt;

    const int t = threadIdx.x;
    const int lane = t & 63;
    const int w = t >> 6;               // wave id 0..3
    const int jj = lane & 31;
    const float* __restrict__ W = ws + W_OFF;

    // register-resident folded weights (coalesced L2-hit loads, once per block)
    float m2col[I1];                    // 64 VGPR
    #pragma unroll
    for (int s = 0; s < I1; ++s)
        m2col[s] = ws[M2F_OFF + s * I2 + jj];
    float m3a[I2], m3b[I2];             // 64 VGPR
    #pragma unroll
    for (int i = 0; i < I2; ++i) {
        m3a[i] = ws[M3F_OFF + i * PK + lane];
        m3b[i] = ws[M3F_OFF + i * PK + 64 + jj];
    }
    const float c1l = ws[C1_OFF + lane];
    const float c2j = ws[C2_OFF + jj];
    const float c30 = ws[C3_OFF + lane];
    const float c31 = ws[C3_OFF + 64 + jj];

    const int r0    = blockIdx.x * RPB;
    const int wbase = r0 & ~(GS - 1);   // b * GS (RPB divides GS)

    for (int rr = 0; rr < RPB; ++rr) {
        const int r = r0 + rr;

        __syncthreads();                // acty/partial/cnt reuse guard
        if (t == 0) cnt = 0;
        __syncthreads();                // cnt=0 visible
        const float mv = mat[r * GS + t];
        if (mv != 0.0f) acty[atomicAdd(&cnt, 1)] = t;   // values exactly 0/1
        const float ux = ws[U_OFF + r * I1 + lane] + c1l;
        __syncthreads();                // compaction complete
        const int n = cnt;

        float acc0 = 0.f, acc1 = 0.f;

        // 2-deep software pipeline on the W row loads
        int p = w;
        float wv0 = (p     < n) ? W[(wbase + acty[p    ]) * I1 + lane] : 0.f;
        float wv1 = (p + 4 < n) ? W[(wbase + acty[p + 4]) * I1 + lane] : 0.f;
        while (p < n) {
            const float wv2 = (p + 8 < n) ? W[(wbase + acty[p + 8]) * I1 + lane] : 0.f;

            // Layer 1 (register): lane holds H1[lane]
            const float h1 = fmaxf(ux + wv0, 0.f);

            // Layer 2: full dot for column jj via 64 uniform readlane
            // broadcasts; 4 interleaved chains (dep 16).
            float a0 = 0.f, a1 = 0.f, a2 = 0.f, a3 = 0.f;
            #pragma unroll
            for (int s = 0; s < I1; s += 4) {
                a0 = fmaf(rdlane(h1, s + 0), m2col[s + 0], a0);
                a1 = fmaf(rdlane(h1, s + 1), m2col[s + 1], a1);
                a2 = fmaf(rdlane(h1, s + 2), m2col[s + 2], a2);
                a3 = fmaf(rdlane(h1, s + 3), m2col[s + 3], a3);
            }
            // lane l now holds H2[l & 31] (duplicated across halves)
            const float h2 = fmaxf((a0 + a1) + (a2 + a3) + c2j, 0.f);

            // Layer 3: 32 uniform broadcasts of H2[i]; each serves both
            // output columns k0=lane, k1=64+jj. Dual chains each.
            float d0a = c30, d0b = 0.f, d1a = c31, d1b = 0.f;
            #pragma unroll
            for (int i = 0; i < I2; i += 2) {
                const float he = rdlane(h2, i);
                const float ho = rdlane(h2, i + 1);
                d0a = fmaf(he, m3a[i],     d0a);
                d0b = fmaf(ho, m3a[i + 1], d0b);
                d1a = fmaf(he, m3b[i],     d1a);
                d1b = fmaf(ho, m3b[i + 1], d1b);
            }
            acc0 += fmaxf(d0a + d0b, 0.f);
            acc1 += fmaxf(d1a + d1b, 0.f);

            wv0 = wv1;
            wv1 = wv2;
            p += 4;
        }

        partial[w][lane] = acc0;
        if (lane < 32) partial[w][64 + lane] = acc1;  // halves hold identical acc1
        __syncthreads();

        if (t < PK) {
            float v = (partial[0][t] + partial[1][t] +
                       partial[2][t] + partial[3][t]) * KDIV_INV;
            v = fminf(fmaxf(v, -1.0f), 1.0f);
            out[r * PARAM + KC + t] = v;
        }
    }
}

extern "C" void kernel_launch(void* const* d_in, const int* in_sizes, int n_in,
                              void* d_out, int out_size, void* d_ws, size_t ws_size,
                              hipStream_t stream) {
    const float* mat = (const float*)d_in[0];
    const float* val = (const float*)d_in[1];
    const float* M1  = (const float*)d_in[2];
    const float* B1  = (const float*)d_in[3];
    const float* M2  = (const float*)d_in[4];
    const float* B2  = (const float*)d_in[5];
    const float* M3  = (const float*)d_in[6];
    const float* B3  = (const float*)d_in[7];
    const float* g1  = (const float*)d_in[8];
    const float* b1  = (const float*)d_in[9];
    const float* m1  = (const float*)d_in[10];
    const float* v1  = (const float*)d_in[11];
    const float* g2  = (const float*)d_in[12];
    const float* b2  = (const float*)d_in[13];
    const float* m2  = (const float*)d_in[14];
    const float* v2  = (const float*)d_in[15];
    const float* g3  = (const float*)d_in[16];
    const float* b3  = (const float*)d_in[17];
    const float* m3  = (const float*)d_in[18];
    const float* v3  = (const float*)d_in[19];

    float* ws  = (float*)d_ws;
    float* out = (float*)d_out;

    hipLaunchKernelGGL(glmlp_precompute, dim3(NROWS + 1), dim3(256), 0, stream,
                       val, M1, B1, M2, B2, M3, B3,
                       g1, b1, m1, v1, g2, b2, m2, v2, g3, b3, m3, v3,
                       ws, out);

    hipLaunchKernelGGL(glmlp_pairs, dim3(NROWS / RPB), dim3(256), 0, stream,
                       mat, ws, out);
}

// Round 8
// 110.571 us; speedup vs baseline: 1.0245x; 1.0245x over previous
//
#include <hip/hip_runtime.h>

// Problem constants (fixed by reference)
#define GS    256
#define PARAM 128
#define KC    32
#define I1    64
#define I2    32
#define PK    96        // PARAM - KC
#define B_    4
#define NROWS (B_ * GS) // 1024
#define EPS   1e-3f
#define KDIV_INV (1.0f / 16.0f)

// Workspace layout (float offsets)
constexpr int U_OFF   = 0;                   // NROWS*I1
constexpr int W_OFF   = NROWS * I1;
constexpr int M2F_OFF = 2 * NROWS * I1;      // I1*I2
constexpr int C2_OFF  = M2F_OFF + I1 * I2;   // I2
constexpr int M3F_OFF = C2_OFF + I2;         // I2*PK
constexpr int C3_OFF  = M3F_OFF + I2 * PK;   // PK
constexpr int C1_OFF  = C3_OFF + PK;         // I1

__device__ __forceinline__ float rdlane(float v, int l) {
    return __uint_as_float(__builtin_amdgcn_readlane(__float_as_uint(v), l));
}

// Kernel A: one block per row. 256 thr = 64 i-lanes x 4 quarter-dots.
// u = val.(M1top - M1bot) = T - W; compute T and W (1 load per MAC each).
__global__ __launch_bounds__(256) void glmlp_precompute(
    const float* __restrict__ val, const float* __restrict__ M1,
    const float* __restrict__ B1,
    const float* __restrict__ M2, const float* __restrict__ B2,
    const float* __restrict__ M3, const float* __restrict__ B3,
    const float* __restrict__ g1, const float* __restrict__ b1,
    const float* __restrict__ m1, const float* __restrict__ v1,
    const float* __restrict__ g2, const float* __restrict__ b2,
    const float* __restrict__ m2, const float* __restrict__ v2,
    const float* __restrict__ g3, const float* __restrict__ b3,
    const float* __restrict__ m3, const float* __restrict__ v3,
    float* __restrict__ ws, float* __restrict__ out)
{
    const int blk = blockIdx.x;
    const int t = threadIdx.x;

    if (blk < NROWS) {
        __shared__ float vrow[PARAM];
        __shared__ float red[4][I1];
        const int r = blk;
        if (t < PARAM) vrow[t] = val[r * PARAM + t];
        // exact copy: con = val[:, :, :KC] (direct from global; no barrier dep)
        if (t < KC) out[r * PARAM + t] = val[r * PARAM + t];
        __syncthreads();

        const int i = t & (I1 - 1);
        const int q = t >> 6;                         // 0..3
        // q=0,1 -> T (M1 top half); q=2,3 -> W (M1 bottom half)
        const float* __restrict__ Mb = M1 + ((q >> 1) ? (PARAM * I1) : 0);
        const int p0 = (q & 1) * 64;
        float aa = 0.f, bb = 0.f;                     // dual chains (dep 32)
        #pragma unroll 8
        for (int p = 0; p < 64; p += 2) {
            aa = fmaf(vrow[p0 + p],     Mb[(p0 + p) * I1 + i],     aa);
            bb = fmaf(vrow[p0 + p + 1], Mb[(p0 + p + 1) * I1 + i], bb);
        }
        red[q][i] = aa + bb;
        __syncthreads();

        if (q == 0) {
            const float T  = red[0][i] + red[1][i];
            const float Wv = red[2][i] + red[3][i];
            const float s1 = g1[i] * rsqrtf(v1[i] + EPS);
            ws[U_OFF + r * I1 + i] = (T - Wv) * s1;
            ws[W_OFF + r * I1 + i] = Wv * s1;
        }
    } else {
        // BN folding block
        if (t < I1) {
            const float s1 = g1[t] * rsqrtf(v1[t] + EPS);
            ws[C1_OFF + t] = B1[t] * s1 + b1[t] - m1[t] * s1;
        }
        if (t < I2) {
            const float s2 = g2[t] * rsqrtf(v2[t] + EPS);
            ws[C2_OFF + t] = B2[t] * s2 + b2[t] - m2[t] * s2;
        }
        if (t < PK) {
            const float s3 = g3[t] * rsqrtf(v3[t] + EPS);
            ws[C3_OFF + t] = B3[t] * s3 + b3[t] - m3[t] * s3;
        }
        for (int idx = t; idx < I1 * I2; idx += 256) {
            const int j = idx & (I2 - 1);
            const float s2 = g2[j] * rsqrtf(v2[j] + EPS);
            ws[M2F_OFF + idx] = M2[idx] * s2;
        }
        for (int idx = t; idx < I2 * PK; idx += 256) {
            const int k = idx % PK;
            const float s3 = g3[k] * rsqrtf(v3[k] + EPS);
            ws[M3F_OFF + idx] = M3[idx] * s3;
        }
    }
}

// Kernel B: one block per (b,x) row; 4 waves; wave w owns pairs p = w mod 4
// end-to-end. All cross-lane broadcasts via v_readlane (wave-uniform index,
// SGPR result -> scalar operand of v_fma). Weights live in per-lane
// REGISTERS (proven to allocate in this standalone context; the fused/cg
// variants spilled to 80 VGPR three rounds running):
//   lane (h=lane>>5, j=lane&31): m2col[s]=M2f[s][j] (full column, dup across h)
//   m3a[i]=M3f[i][lane] (k=lane), m3b[i]=M3f[i][64+j] (k=64+j, dup across h)
// LDS ~2.6 KB; 2 barriers total.
// 1024 blocks at 2-3 blocks/CU: inter-block TLP hides the weight preload and
// W-load latency (r7 measured: collapsing to 1 persistent block/CU costs
// +5.5 µs — TLP > preload amortization for this shape).
// W prefetch depth 2 (issue load for pair p+8 before body p).
__global__ __launch_bounds__(256) void glmlp_pairs(
    const float* __restrict__ mat, const float* __restrict__ ws,
    float* __restrict__ out)
{
    __shared__ int   acty[GS];          // 1 KB
    __shared__ float partial[4][PK];    // 1.5 KB
    __shared__ int   cnt;

    const int r = blockIdx.x;
    const int t = threadIdx.x;
    const int lane = t & 63;
    const int w = t >> 6;               // wave id 0..3
    const int jj = lane & 31;
    const int wbase = r & ~(GS - 1);    // b * GS
    const float* __restrict__ W = ws + W_OFF;

    if (t == 0) cnt = 0;
    const float mv = mat[r * GS + t];

    // register-resident folded weights (coalesced L2-hit loads, once per block)
    float m2col[I1];                    // 64 VGPR
    #pragma unroll
    for (int s = 0; s < I1; ++s)
        m2col[s] = ws[M2F_OFF + s * I2 + jj];
    float m3a[I2], m3b[I2];             // 64 VGPR
    #pragma unroll
    for (int i = 0; i < I2; ++i) {
        m3a[i] = ws[M3F_OFF + i * PK + lane];
        m3b[i] = ws[M3F_OFF + i * PK + 64 + jj];
    }
    const float ux  = ws[U_OFF + r * I1 + lane] + ws[C1_OFF + lane];
    const float c2j = ws[C2_OFF + jj];
    const float c30 = ws[C3_OFF + lane];
    const float c31 = ws[C3_OFF + 64 + jj];

    __syncthreads();                    // cnt=0 visible
    // compact the mask row (values are exactly 0.0/1.0)
    if (mv != 0.0f) acty[atomicAdd(&cnt, 1)] = t;
    __syncthreads();
    const int n = cnt;

    float acc0 = 0.f, acc1 = 0.f;

    // 2-deep software pipeline on the W row loads
    int p = w;
    float wv0 = (p     < n) ? W[(wbase + acty[p    ]) * I1 + lane] : 0.f;
    float wv1 = (p + 4 < n) ? W[(wbase + acty[p + 4]) * I1 + lane] : 0.f;
    while (p < n) {
        const float wv2 = (p + 8 < n) ? W[(wbase + acty[p + 8]) * I1 + lane] : 0.f;

        // Layer 1 (register): lane holds H1[lane]
        const float h1 = fmaxf(ux + wv0, 0.f);

        // Layer 2: every lane computes the FULL dot for its column jj via
        // 64 uniform readlane broadcasts; 4 interleaved chains (dep 16).
        float a0 = 0.f, a1 = 0.f, a2 = 0.f, a3 = 0.f;
        #pragma unroll
        for (int s = 0; s < I1; s += 4) {
            a0 = fmaf(rdlane(h1, s + 0), m2col[s + 0], a0);
            a1 = fmaf(rdlane(h1, s + 1), m2col[s + 1], a1);
            a2 = fmaf(rdlane(h1, s + 2), m2col[s + 2], a2);
            a3 = fmaf(rdlane(h1, s + 3), m2col[s + 3], a3);
        }
        // lane l now holds H2[l & 31] (duplicated across halves)
        const float h2 = fmaxf((a0 + a1) + (a2 + a3) + c2j, 0.f);

        // Layer 3: 32 uniform broadcasts of H2[i] (lane i holds H2[i], i<32);
        // each serves both output columns k0=lane, k1=64+jj. Dual chains each.
        float d0a = c30, d0b = 0.f, d1a = c31, d1b = 0.f;
        #pragma unroll
        for (int i = 0; i < I2; i += 2) {
            const float he = rdlane(h2, i);
            const float ho = rdlane(h2, i + 1);
            d0a = fmaf(he, m3a[i],     d0a);
            d0b = fmaf(ho, m3a[i + 1], d0b);
            d1a = fmaf(he, m3b[i],     d1a);
            d1b = fmaf(ho, m3b[i + 1], d1b);
        }
        acc0 += fmaxf(d0a + d0b, 0.f);
        acc1 += fmaxf(d1a + d1b, 0.f);

        wv0 = wv1;
        wv1 = wv2;
        p += 4;
    }

    partial[w][lane] = acc0;
    if (lane < 32) partial[w][64 + lane] = acc1;   // halves hold identical acc1
    __syncthreads();

    if (t < PK) {
        float v = (partial[0][t] + partial[1][t] + partial[2][t] + partial[3][t])
                  * KDIV_INV;
        v = fminf(fmaxf(v, -1.0f), 1.0f);
        out[r * PARAM + KC + t] = v;
    }
}

extern "C" void kernel_launch(void* const* d_in, const int* in_sizes, int n_in,
                              void* d_out, int out_size, void* d_ws, size_t ws_size,
                              hipStream_t stream) {
    const float* mat = (const float*)d_in[0];
    const float* val = (const float*)d_in[1];
    const float* M1  = (const float*)d_in[2];
    const float* B1  = (const float*)d_in[3];
    const float* M2  = (const float*)d_in[4];
    const float* B2  = (const float*)d_in[5];
    const float* M3  = (const float*)d_in[6];
    const float* B3  = (const float*)d_in[7];
    const float* g1  = (const float*)d_in[8];
    const float* b1  = (const float*)d_in[9];
    const float* m1  = (const float*)d_in[10];
    const float* v1  = (const float*)d_in[11];
    const float* g2  = (const float*)d_in[12];
    const float* b2  = (const float*)d_in[13];
    const float* m2  = (const float*)d_in[14];
    const float* v2  = (const float*)d_in[15];
    const float* g3  = (const float*)d_in[16];
    const float* b3  = (const float*)d_in[17];
    const float* m3  = (const float*)d_in[18];
    const float* v3  = (const float*)d_in[19];

    float* ws  = (float*)d_ws;
    float* out = (float*)d_out;

    hipLaunchKernelGGL(glmlp_precompute, dim3(NROWS + 1), dim3(256), 0, stream,
                       val, M1, B1, M2, B2, M3, B3,
                       g1, b1, m1, v1, g2, b2, m2, v2, g3, b3, m3, v3,
                       ws, out);

    hipLaunchKernelGGL(glmlp_pairs, dim3(NROWS), dim3(256), 0, stream,
                       mat, ws, out);
}